// Round 2
// baseline (225.246 us; speedup 1.0000x reference)
//
#include <hip/hip_runtime.h>
#include <math.h>

// Composite of 1000 float32-rounded rotation steps applied as ONE 2x2 matmul.
// Streaming kernel: 128 MiB in + 128 MiB out. Each thread processes two
// float4s (4 states, 32 B) with fully-coalesced within-block layout.
__global__ __launch_bounds__(256) void lin2d_rot_kernel(
    const float4* __restrict__ in, float4* __restrict__ out,
    int n4, float C, float S) {
    // Block handles 512 consecutive float4s: tid and tid+256.
    int base = blockIdx.x * 512 + threadIdx.x;

    int i0 = base;
    int i1 = base + 256;

    if (i0 < n4) {
        float4 v = in[i0];
        float4 r;
        r.x =  C * v.x + S * v.y;
        r.y = -S * v.x + C * v.y;
        r.z =  C * v.z + S * v.w;
        r.w = -S * v.z + C * v.w;
        out[i0] = r;
    }
    if (i1 < n4) {
        float4 v = in[i1];
        float4 r;
        r.x =  C * v.x + S * v.y;
        r.y = -S * v.x + C * v.y;
        r.z =  C * v.z + S * v.w;
        r.w = -S * v.z + C * v.w;
        out[i1] = r;
    }
}

extern "C" void kernel_launch(void* const* d_in, const int* in_sizes, int n_in,
                              void* d_out, int out_size, void* d_ws, size_t ws_size,
                              hipStream_t stream) {
    (void)d_ws; (void)ws_size; (void)n_in; (void)out_size;

    // Per-step float32-rounded constants, composed exactly in double:
    // M = [[c,s],[-s,c]]; M^1000 = r^1000 * R(1000*phi).
    const double theta = M_PI / 100.0;
    const float cf = (float)cos(theta);
    const float sf = (float)sin(theta);
    const double r   = sqrt((double)cf * cf + (double)sf * sf);
    const double phi = atan2((double)sf, (double)cf);
    const double scale = pow(r, 1000.0);
    const double ang   = 1000.0 * phi;
    const float C = (float)(scale * cos(ang));
    const float S = (float)(scale * sin(ang));

    const float4* in  = (const float4*)d_in[0];
    float4*       out = (float4*)d_out;
    const int n_elems = in_sizes[0];      // 16777216 * 2 floats
    const int n4 = n_elems / 4;           // 8,388,608 float4s

    // 512 float4s per block.
    const int grid = (n4 + 511) / 512;    // 16384 blocks
    lin2d_rot_kernel<<<grid, 256, 0, stream>>>(in, out, n4, C, S);
}